// Round 1
// baseline (110.614 us; speedup 1.0000x reference)
//
#include <hip/hip_runtime.h>

// ---------------------------------------------------------------------------
// 9-qubit circuit per 3x3 patch. One patch per wave64.
// Qubit q in 0..5 -> lane bit (5-q); qubit 6..8 -> register-index bit (8-q).
// Algebraic reductions applied (exact):
//   * RX embedding + layer-0 Rot folded into product-state init.
//   * Layer-1 CNOT ring dropped; observable becomes Z0 Z1 Z3 Z5 Z7.
//   * Layer-1 Rots on qubits {2,4,6,8} dropped (commute with observable).
// ---------------------------------------------------------------------------

__global__ void rot_precompute(const float* __restrict__ w, float* __restrict__ rot) {
    int t = threadIdx.x;
    if (t < 18) {
        float phi = w[t * 3 + 0], th = w[t * 3 + 1], om = w[t * 3 + 2];
        float st, ct; __sincosf(0.5f * th, &st, &ct);
        float sp, cp; __sincosf(0.5f * (phi + om), &sp, &cp);
        float sm, cm; __sincosf(0.5f * (phi - om), &sm, &cm);
        float* g = rot + t * 8;
        // u00 = e^{-i(phi+om)/2} ct ; u01 = -e^{+i(phi-om)/2} st
        // u10 = e^{-i(phi-om)/2} st ; u11 = e^{+i(phi+om)/2} ct
        g[0] =  ct * cp; g[1] = -ct * sp;
        g[2] = -st * cm; g[3] = -st * sm;
        g[4] =  st * cm; g[5] = -st * sm;
        g[6] =  ct * cp; g[7] =  ct * sp;
    }
}

// CNOT, control in lane bit, target in lane bit (mask TM)
template <int TM>
__device__ __forceinline__ void cnot_ll(float (&ar)[8], float (&ai)[8], bool ctrl) {
#pragma unroll
    for (int r = 0; r < 8; ++r) {
        float pr_ = __shfl_xor(ar[r], TM, 64);
        float pi_ = __shfl_xor(ai[r], TM, 64);
        ar[r] = ctrl ? pr_ : ar[r];
        ai[r] = ctrl ? pi_ : ai[r];
    }
}

// CNOT, control in lane, target in register bit TM
template <int TM>
__device__ __forceinline__ void cnot_lr(float (&ar)[8], float (&ai)[8], bool ctrl) {
#pragma unroll
    for (int r = 0; r < 8; ++r) {
        if (!(r & TM)) {
            int r1 = r | TM;
            float t0r = ar[r], t0i = ai[r], t1r = ar[r1], t1i = ai[r1];
            ar[r]  = ctrl ? t1r : t0r;  ai[r]  = ctrl ? t1i : t0i;
            ar[r1] = ctrl ? t0r : t1r;  ai[r1] = ctrl ? t0i : t1i;
        }
    }
}

// CNOT, control reg bit CM, target reg bit TM (pure register permutation)
template <int CM, int TM>
__device__ __forceinline__ void cnot_rr(float (&ar)[8], float (&ai)[8]) {
#pragma unroll
    for (int r = 0; r < 8; ++r) {
        if ((r & CM) && !(r & TM)) {
            int r1 = r | TM;
            float tr = ar[r]; ar[r] = ar[r1]; ar[r1] = tr;
            float ti = ai[r]; ai[r] = ai[r1]; ai[r1] = ti;
        }
    }
}

// CNOT, control reg bit CM, target lane mask TL
template <int CM, int TL>
__device__ __forceinline__ void cnot_rl(float (&ar)[8], float (&ai)[8]) {
#pragma unroll
    for (int r = 0; r < 8; ++r) {
        if (r & CM) {
            ar[r] = __shfl_xor(ar[r], TL, 64);
            ai[r] = __shfl_xor(ai[r], TL, 64);
        }
    }
}

// 1-qubit gate on lane-qubit (mask M). g = 8 floats (u00,u01,u10,u11 as re,im).
template <int M>
__device__ __forceinline__ void rot_lane(float (&ar)[8], float (&ai)[8],
                                         const float* __restrict__ g, int lane) {
    float u00r = g[0], u00i = g[1], u01r = g[2], u01i = g[3];
    float u10r = g[4], u10i = g[5], u11r = g[6], u11i = g[7];
    bool b = (lane & M) != 0;
    // own amp has bit=b -> coef U[b][b]; partner has bit=1-b -> coef U[b][1-b]
    float cAr = b ? u11r : u00r, cAi = b ? u11i : u00i;
    float cBr = b ? u10r : u01r, cBi = b ? u10i : u01i;
#pragma unroll
    for (int r = 0; r < 8; ++r) {
        float pr_ = __shfl_xor(ar[r], M, 64);
        float pi_ = __shfl_xor(ai[r], M, 64);
        float o_r = ar[r], o_i = ai[r];
        ar[r] = cAr * o_r - cAi * o_i + cBr * pr_ - cBi * pi_;
        ai[r] = cAr * o_i + cAi * o_r + cBr * pi_ + cBi * pr_;
    }
}

// 1-qubit gate on register-qubit (bit M)
template <int M>
__device__ __forceinline__ void rot_reg(float (&ar)[8], float (&ai)[8],
                                        const float* __restrict__ g) {
    float u00r = g[0], u00i = g[1], u01r = g[2], u01i = g[3];
    float u10r = g[4], u10i = g[5], u11r = g[6], u11i = g[7];
#pragma unroll
    for (int r = 0; r < 8; ++r) {
        if (!(r & M)) {
            int r1 = r | M;
            float a0r = ar[r], a0i = ai[r], a1r = ar[r1], a1i = ai[r1];
            ar[r]  = u00r * a0r - u00i * a0i + u01r * a1r - u01i * a1i;
            ai[r]  = u00r * a0i + u00i * a0r + u01r * a1i + u01i * a1r;
            ar[r1] = u10r * a0r - u10i * a0i + u11r * a1r - u11i * a1i;
            ai[r1] = u10r * a0i + u10i * a0r + u11r * a1i + u11i * a1r;
        }
    }
}

__global__ __launch_bounds__(256) void qsim(const float* __restrict__ x,
                                            const float* __restrict__ rot,
                                            float* __restrict__ out) {
    const int lane = threadIdx.x & 63;
    const int wv   = threadIdx.x >> 6;
    const int p    = blockIdx.x * 4 + wv;          // patch id, 0..32767
    const int b = p >> 12, h = (p >> 6) & 63, w = p & 63;

    // v_q = Rot0_q * RX(a_q) * |0>, a 2-vector per qubit
    float v0r[9], v0i[9], v1r[9], v1i[9];
#pragma unroll
    for (int q = 0; q < 9; ++q) {
        const int i = h + q / 3 - 1, j = w + q % 3 - 1;
        float a = 0.f;
        if ((unsigned)i < 64u && (unsigned)j < 64u) a = x[(b << 12) + (i << 6) + j];
        float s, c; __sincosf(0.5f * a, &s, &c);   // RX column0 = [c, -i s]
        const float* g = rot + q * 8;
        float u00r = g[0], u00i = g[1], u01r = g[2], u01i = g[3];
        float u10r = g[4], u10i = g[5], u11r = g[6], u11i = g[7];
        v0r[q] = u00r * c + u01i * s;
        v0i[q] = u00i * c - u01r * s;
        v1r[q] = u10r * c + u11i * s;
        v1i[q] = u10i * c - u11r * s;
    }

    // product over lane qubits 0..5
    float lpr = 1.f, lpi = 0.f;
#pragma unroll
    for (int q = 0; q < 6; ++q) {
        int bit = (lane >> (5 - q)) & 1;
        float fr = bit ? v1r[q] : v0r[q];
        float fi = bit ? v1i[q] : v0i[q];
        float nr = lpr * fr - lpi * fi;
        float ni = lpr * fi + lpi * fr;
        lpr = nr; lpi = ni;
    }
    // pair products of q6,q7
    float tpr[4], tpi[4];
#pragma unroll
    for (int t = 0; t < 4; ++t) {
        int b6 = (t >> 1) & 1, b7 = t & 1;
        float f6r = b6 ? v1r[6] : v0r[6], f6i = b6 ? v1i[6] : v0i[6];
        float f7r = b7 ? v1r[7] : v0r[7], f7i = b7 ? v1i[7] : v0i[7];
        tpr[t] = f6r * f7r - f6i * f7i;
        tpi[t] = f6r * f7i + f6i * f7r;
    }
    // full amplitudes: reg index r = (b6,b7,b8)
    float ar[8], ai[8];
#pragma unroll
    for (int r = 0; r < 8; ++r) {
        int t = r >> 1, b8 = r & 1;
        float f8r = b8 ? v1r[8] : v0r[8], f8i = b8 ? v1i[8] : v0i[8];
        float qr = tpr[t] * f8r - tpi[t] * f8i;
        float qi = tpr[t] * f8i + tpi[t] * f8r;
        ar[r] = lpr * qr - lpi * qi;
        ai[r] = lpr * qi + lpi * qr;
    }

    // layer-0 CNOT ring (r=1): (0,1)(1,2)(2,3)(3,4)(4,5)(5,6)(6,7)(7,8)(8,0)
    cnot_ll<16>(ar, ai, (lane & 32) != 0);
    cnot_ll<8 >(ar, ai, (lane & 16) != 0);
    cnot_ll<4 >(ar, ai, (lane & 8)  != 0);
    cnot_ll<2 >(ar, ai, (lane & 4)  != 0);
    cnot_ll<1 >(ar, ai, (lane & 2)  != 0);
    cnot_lr<4 >(ar, ai, (lane & 1)  != 0);
    cnot_rr<4, 2>(ar, ai);
    cnot_rr<2, 1>(ar, ai);
    cnot_rl<1, 32>(ar, ai);

    // layer-1 Rots, only qubits {0,1,3,5,7} survive the pruned observable
    rot_lane<32>(ar, ai, rot + (9 + 0) * 8, lane);
    rot_lane<16>(ar, ai, rot + (9 + 1) * 8, lane);
    rot_lane<4 >(ar, ai, rot + (9 + 3) * 8, lane);
    rot_lane<1 >(ar, ai, rot + (9 + 5) * 8, lane);
    rot_reg<2  >(ar, ai, rot + (9 + 7) * 8);

    // measure <Z0 Z1 Z3 Z5 Z7>: lane-bit parity mask 32+16+4+1=53, reg bit 1 (q7)
    int lp = __popc(lane & 53) & 1;
    float acc = 0.f;
#pragma unroll
    for (int r = 0; r < 8; ++r) {
        float m = ar[r] * ar[r] + ai[r] * ai[r];
        int par = lp ^ ((r >> 1) & 1);
        acc += par ? -m : m;
    }
#pragma unroll
    for (int off = 32; off > 0; off >>= 1) acc += __shfl_xor(acc, off, 64);
    if (lane == 0) out[p] = acc;
}

extern "C" void kernel_launch(void* const* d_in, const int* in_sizes, int n_in,
                              void* d_out, int out_size, void* d_ws, size_t ws_size,
                              hipStream_t stream) {
    const float* x   = (const float*)d_in[0];   // (8,1,64,64) fp32
    const float* wts = (const float*)d_in[1];   // (2,9,3) fp32
    float* out = (float*)d_out;                 // (8,1,64,64) fp32
    float* rotm = (float*)d_ws;                 // 18 gates * 8 floats = 576 B scratch

    rot_precompute<<<1, 64, 0, stream>>>(wts, rotm);
    qsim<<<8192, 256, 0, stream>>>(x, rotm, out);
}

// Round 2
// 57.195 us; speedup vs baseline: 1.9340x; 1.9340x over previous
//
#include <hip/hip_runtime.h>

// ---------------------------------------------------------------------------
// One THREAD per 3x3 patch (32768 patches). No statevector.
//
// Derivation (exact):
//  * RX embedding + layer-0 Rot give a product state with per-qubit 2-vectors
//    v_q = Rot0_q * RX(a_q) * |0>.
//  * Layer-0 CNOT ring (r=1) is a GF(2)-linear basis permutation sigma:
//      amp[x] = prod_q v_q[s_q(x)],  s_0=x0^x8, s_1=x0^x1^x8, s_q=x_{q-1}^x_q.
//  * Layer-1 CNOT ring (r=2) commutes through Z0 -> observable Z0 Z1 Z3 Z5 Z7;
//    layer-1 Rots on {2,4,6,8} commute out; those on Q={0,1,3,5,7} conjugate
//    Z into M_q = [[cos t, -sin t e^{i phi}], [-sin t e^{-i phi}, -cos t]].
//  * E = sum_{x,x'} conj(amp[x]) (prod M_q ⊗ deltas) amp[x'] is a ring tensor
//    network, bond dim <= 4. Fix beta = x8 = x'8 (2 values), contract the
//    chain site 0..7, close with site 8. Messages are Hermitian 2x2:
//    {p00, p11, p01=pr+i*pi}. Per-qubit factor c_q(a,b) = conj(v_q[a])*v_q[b]
//    is also Hermitian: {c00, c11, c01}.
// ---------------------------------------------------------------------------

struct H4 { float p00, p11, pr, pi; };

// R(g,g') = sum_{a,b} P[a,b] * c(a^g, b^g')   (Hermitian in/out)
__device__ __forceinline__ H4 hsc(H4 P, float c00, float c11, float cr, float ci) {
    H4 R;
    float t1 = P.pr * cr - P.pi * ci;
    float t2 = P.pr * cr + P.pi * ci;
    R.p00 = P.p00 * c00 + P.p11 * c11 + 2.f * t1;
    R.p11 = P.p00 * c11 + P.p11 * c00 + 2.f * t2;
    R.pr  = (P.p00 + P.p11) * cr + P.pr * (c00 + c11);
    R.pi  = (P.p00 - P.p11) * ci + P.pi * (c00 - c11);
    return R;
}

// elementwise multiply by M = [[m00, mr+i*mi], [mr-i*mi, -m00]]
__device__ __forceinline__ H4 mhad(H4 P, float m00, float mr, float mi) {
    H4 R;
    R.p00 =  P.p00 * m00;
    R.p11 = -P.p11 * m00;
    R.pr  = P.pr * mr - P.pi * mi;
    R.pi  = P.pr * mi + P.pi * mr;
    return R;
}

// inner(x,x') = sum_g m_g * c(g^x, g^x')
__device__ __forceinline__ H4 expand2(float m0, float m1, float c00, float c11, float cr, float ci) {
    H4 R;
    R.p00 = m0 * c00 + m1 * c11;
    R.p11 = m0 * c11 + m1 * c00;
    R.pr  = (m0 + m1) * cr;
    R.pi  = (m0 - m1) * ci;
    return R;
}

__global__ __launch_bounds__(64) void qsim(const float* __restrict__ x,
                                           const float* __restrict__ wts,
                                           float* __restrict__ out) {
    __shared__ float u[9][8];   // layer-0 Rot matrices (u00,u01,u10,u11 re/im)
    __shared__ float mq[5][3];  // M for Q={0,1,3,5,7}: m00, m01r, m01i

    const int t = threadIdx.x;
    if (t < 9) {
        float phi = wts[t * 3 + 0], th = wts[t * 3 + 1], om = wts[t * 3 + 2];
        float st, ct; __sincosf(0.5f * th, &st, &ct);
        float sp, cp; __sincosf(0.5f * (phi + om), &sp, &cp);
        float sm, cm; __sincosf(0.5f * (phi - om), &sm, &cm);
        u[t][0] =  ct * cp; u[t][1] = -ct * sp;
        u[t][2] = -st * cm; u[t][3] = -st * sm;
        u[t][4] =  st * cm; u[t][5] = -st * sm;
        u[t][6] =  ct * cp; u[t][7] =  ct * sp;
    } else if (t < 14) {
        const int k = t - 9;
        const int q = (k == 0) ? 0 : 2 * k - 1;   // {0,1,3,5,7}
        float phi = wts[27 + q * 3 + 0], th = wts[27 + q * 3 + 1];
        float sth, cth; __sincosf(th, &sth, &cth);
        float sph, cph; __sincosf(phi, &sph, &cph);
        mq[k][0] = cth;
        mq[k][1] = -sth * cph;
        mq[k][2] = -sth * sph;
    }
    __syncthreads();

    const int p = blockIdx.x * 64 + t;           // patch id 0..32767
    const int b = p >> 12, h = (p >> 6) & 63, w = p & 63;

    // per-qubit Hermitian factor tables c_q(a,b) = conj(v_q[a]) v_q[b]
    float c00[9], c11[9], cr[9], ci[9];
#pragma unroll
    for (int q = 0; q < 9; ++q) {
        const int i = h + q / 3 - 1, j = w + q % 3 - 1;
        float a = 0.f;
        if ((unsigned)i < 64u && (unsigned)j < 64u) a = x[(b << 12) + (i << 6) + j];
        float s, c; __sincosf(0.5f * a, &s, &c);      // RX|0> = (c, -i s)
        float v0r = u[q][0] * c + u[q][3] * s;
        float v0i = u[q][1] * c - u[q][2] * s;
        float v1r = u[q][4] * c + u[q][7] * s;
        float v1i = u[q][5] * c - u[q][6] * s;
        c00[q] = v0r * v0r + v0i * v0i;
        c11[q] = v1r * v1r + v1i * v1i;
        cr[q]  = v0r * v1r + v0i * v1i;
        ci[q]  = v0r * v1i - v0i * v1r;
    }

    float E = 0.f;
#pragma unroll
    for (int beta = 0; beta < 2; ++beta) {
        // site 0: msg0 = M0 o c0(x0^beta, x'0^beta)
        H4 P;
        if (beta == 0) P = H4{c00[0], c11[0], cr[0], ci[0]};
        else           P = H4{c11[0], c00[0], cr[0], -ci[0]};
        P = mhad(P, mq[0][0], mq[0][1], mq[0][2]);
        // site 1: inner(x1,x'1) = R(x1^beta, x'1^beta), R = hsc(msg0, c1)
        H4 R = hsc(P, c00[1], c11[1], cr[1], ci[1]);
        if (beta == 1) { float tmp = R.p00; R.p00 = R.p11; R.p11 = tmp; R.pi = -R.pi; }
        P = mhad(R, mq[1][0], mq[1][1], mq[1][2]);
        // site 2 (delta): m2[g] = diag of hsc(msg1, c2)
        R = hsc(P, c00[2], c11[2], cr[2], ci[2]);
        // site 3
        P = mhad(expand2(R.p00, R.p11, c00[3], c11[3], cr[3], ci[3]),
                 mq[2][0], mq[2][1], mq[2][2]);
        // site 4 (delta)
        R = hsc(P, c00[4], c11[4], cr[4], ci[4]);
        // site 5
        P = mhad(expand2(R.p00, R.p11, c00[5], c11[5], cr[5], ci[5]),
                 mq[3][0], mq[3][1], mq[3][2]);
        // site 6 (delta)
        R = hsc(P, c00[6], c11[6], cr[6], ci[6]);
        // site 7
        P = mhad(expand2(R.p00, R.p11, c00[7], c11[7], cr[7], ci[7]),
                 mq[4][0], mq[4][1], mq[4][2]);
        // close with site 8: E_beta = R(beta,beta) of hsc(msg7, c8)
        R = hsc(P, c00[8], c11[8], cr[8], ci[8]);
        E += (beta == 0) ? R.p00 : R.p11;
    }

    out[p] = E;
}

extern "C" void kernel_launch(void* const* d_in, const int* in_sizes, int n_in,
                              void* d_out, int out_size, void* d_ws, size_t ws_size,
                              hipStream_t stream) {
    const float* x   = (const float*)d_in[0];   // (8,1,64,64) fp32
    const float* wts = (const float*)d_in[1];   // (2,9,3) fp32
    float* out = (float*)d_out;                 // (8,1,64,64) fp32
    qsim<<<512, 64, 0, stream>>>(x, wts, out);
}

// Round 3
// 56.058 us; speedup vs baseline: 1.9732x; 1.0203x over previous
//
#include <hip/hip_runtime.h>

// ---------------------------------------------------------------------------
// One THREAD per 3x3 patch (32768 patches). No statevector. See R2 derivation:
// ring tensor network, bond dim <= 4, Hermitian-compressed messages.
// R3: latency-oriented restructuring. __launch_bounds__(64,1) for register
// room (kernel is wave-starved, ILP is the only latency hiding available),
// pixel prefetch with clamp+select, affine c-tables:
//   c_entry(q; a) = K0 + Kc*cos(a) + Ks*sin(a)
// via c^2=(1+cos a)/2, s^2=(1-cos a)/2, cs=sin(a)/2 with (c,s)=cos/sin(a/2).
// ---------------------------------------------------------------------------

struct H4 { float p00, p11, pr, pi; };

// R(g,g') = sum_{a,b} P[a,b] * c(a^g, b^g')   (Hermitian in/out)
// c packed as float4 {c00, c11, cr, ci}
__device__ __forceinline__ H4 hsc(H4 P, float4 c) {
    H4 R;
    float t1 = P.pr * c.z - P.pi * c.w;
    float t2 = P.pr * c.z + P.pi * c.w;
    R.p00 = P.p00 * c.x + P.p11 * c.y + 2.f * t1;
    R.p11 = P.p00 * c.y + P.p11 * c.x + 2.f * t2;
    R.pr  = (P.p00 + P.p11) * c.z + P.pr * (c.x + c.y);
    R.pi  = (P.p00 - P.p11) * c.w + P.pi * (c.x - c.y);
    return R;
}

// elementwise multiply by M = [[m.x, m.y+i*m.z], [m.y-i*m.z, -m.x]]
__device__ __forceinline__ H4 mhad(H4 P, float4 m) {
    H4 R;
    R.p00 =  P.p00 * m.x;
    R.p11 = -P.p11 * m.x;
    R.pr  = P.pr * m.y - P.pi * m.z;
    R.pi  = P.pr * m.z + P.pi * m.y;
    return R;
}

// inner(x,x') = sum_g m_g * c(g^x, g^x')
__device__ __forceinline__ H4 expand2(float m0, float m1, float4 c) {
    H4 R;
    R.p00 = m0 * c.x + m1 * c.y;
    R.p11 = m0 * c.y + m1 * c.x;
    R.pr  = (m0 + m1) * c.z;
    R.pi  = (m0 - m1) * c.w;
    return R;
}

__global__ __launch_bounds__(64, 1) void qsim(const float* __restrict__ x,
                                              const float* __restrict__ wts,
                                              float* __restrict__ out) {
    __shared__ float4 k0s[9], kcs[9], kss[9];  // affine c-table constants
    __shared__ float4 mqs[5];                  // M for Q={0,1,3,5,7}

    const int t = threadIdx.x;
    const int p = blockIdx.x * 64 + t;           // patch id 0..32767
    const int b = p >> 12, h = (p >> 6) & 63, w = p & 63;

    // prefetch 9 pixels: clamped address, always load, select 0 at border
    float av[9];
#pragma unroll
    for (int q = 0; q < 9; ++q) {
        const int i = h + q / 3 - 1, j = w + q % 3 - 1;
        const int ic = min(max(i, 0), 63), jc = min(max(j, 0), 63);
        float a = x[(b << 12) + (ic << 6) + jc];
        av[q] = ((unsigned)i < 64u && (unsigned)j < 64u) ? a : 0.f;
    }

    if (t < 9) {
        // layer-0 Rot matrix for qubit t
        float phi = wts[t * 3 + 0], th = wts[t * 3 + 1], om = wts[t * 3 + 2];
        float st, ct; __sincosf(0.5f * th, &st, &ct);
        float sp, cp; __sincosf(0.5f * (phi + om), &sp, &cp);
        float sm, cm; __sincosf(0.5f * (phi - om), &sm, &cm);
        float u00r =  ct * cp, u00i = -ct * sp;
        float u01r = -st * cm, u01i = -st * sm;
        float u10r =  st * cm, u10i = -st * sm;
        float u11r =  ct * cp, u11i =  ct * sp;
        // c00 = A00 c^2 + B00 s^2 + C00 cs ; c11 likewise; cr,ci bilinear
        float A00 = u00r * u00r + u00i * u00i, B00 = u01r * u01r + u01i * u01i;
        float C00 = 2.f * (u00r * u01i - u00i * u01r);
        float A11 = u10r * u10r + u10i * u10i, B11 = u11r * u11r + u11i * u11i;
        float C11 = 2.f * (u10r * u11i - u10i * u11r);
        float Pr = u00r * u10r + u00i * u10i, Qr = u01r * u11r + u01i * u11i;
        float Rr = u00r * u11i + u01i * u10r - u00i * u11r - u01r * u10i;
        float Pi = u00r * u10i - u00i * u10r, Qi = u01r * u11i - u01i * u11r;
        float Ri = -u00r * u11r + u01i * u10i - u00i * u11i + u01r * u10r;
        k0s[t] = make_float4(0.5f * (A00 + B00), 0.5f * (A11 + B11),
                             0.5f * (Pr + Qr),   0.5f * (Pi + Qi));
        kcs[t] = make_float4(0.5f * (A00 - B00), 0.5f * (A11 - B11),
                             0.5f * (Pr - Qr),   0.5f * (Pi - Qi));
        kss[t] = make_float4(0.5f * C00, 0.5f * C11, 0.5f * Rr, 0.5f * Ri);
    } else if (t < 14) {
        const int k = t - 9;
        const int q = (k == 0) ? 0 : 2 * k - 1;   // {0,1,3,5,7}
        float phi = wts[27 + q * 3 + 0], th = wts[27 + q * 3 + 1];
        float sth, cth; __sincosf(th, &sth, &cth);
        float sph, cph; __sincosf(phi, &sph, &cph);
        mqs[k] = make_float4(cth, -sth * cph, -sth * sph, 0.f);
    }
    __syncthreads();

    // per-qubit Hermitian factors via affine form
    float4 cq[9];
#pragma unroll
    for (int q = 0; q < 9; ++q) {
        float sa, ca; __sincosf(av[q], &sa, &ca);
        float4 K0 = k0s[q], Kc = kcs[q], Ks = kss[q];
        cq[q].x = K0.x + Kc.x * ca + Ks.x * sa;
        cq[q].y = K0.y + Kc.y * ca + Ks.y * sa;
        cq[q].z = K0.z + Kc.z * ca + Ks.z * sa;
        cq[q].w = K0.w + Kc.w * ca + Ks.w * sa;
    }

    float4 m0 = mqs[0], m1 = mqs[1], m2 = mqs[2], m3 = mqs[3], m4 = mqs[4];

    float E = 0.f;
#pragma unroll
    for (int beta = 0; beta < 2; ++beta) {
        // site 0
        H4 P;
        if (beta == 0) P = H4{cq[0].x, cq[0].y, cq[0].z, cq[0].w};
        else           P = H4{cq[0].y, cq[0].x, cq[0].z, -cq[0].w};
        P = mhad(P, m0);
        // site 1
        H4 R = hsc(P, cq[1]);
        if (beta == 1) { float tmp = R.p00; R.p00 = R.p11; R.p11 = tmp; R.pi = -R.pi; }
        P = mhad(R, m1);
        // site 2 (delta)
        R = hsc(P, cq[2]);
        // site 3
        P = mhad(expand2(R.p00, R.p11, cq[3]), m2);
        // site 4 (delta)
        R = hsc(P, cq[4]);
        // site 5
        P = mhad(expand2(R.p00, R.p11, cq[5]), m3);
        // site 6 (delta)
        R = hsc(P, cq[6]);
        // site 7
        P = mhad(expand2(R.p00, R.p11, cq[7]), m4);
        // close with site 8
        R = hsc(P, cq[8]);
        E += (beta == 0) ? R.p00 : R.p11;
    }

    out[p] = E;
}

extern "C" void kernel_launch(void* const* d_in, const int* in_sizes, int n_in,
                              void* d_out, int out_size, void* d_ws, size_t ws_size,
                              hipStream_t stream) {
    const float* x   = (const float*)d_in[0];   // (8,1,64,64) fp32
    const float* wts = (const float*)d_in[1];   // (2,9,3) fp32
    float* out = (float*)d_out;                 // (8,1,64,64) fp32
    qsim<<<512, 64, 0, stream>>>(x, wts, out);
}